// Round 1
// 211.196 us; speedup vs baseline: 2.9476x; 2.9476x over previous
//
#include <hip/hip_runtime.h>

#define HBITS 19u
#define HSIZE (1u << HBITS)
#define HMASK (HSIZE - 1u)
#define ECAP  (1 << 20)           // extras capacity (pairs); test input needs ~4.4K
#define EMPTY64 0xFFFFFFFFFFFFFFFFull

constexpr int CD = 41, CH = 1024, CW = 1024;

// ---------------- hash table: 64-bit records (idx<<32 | lin), linear probe ----------------

__global__ __launch_bounds__(256) void fill_table(unsigned long long* __restrict__ tab,
                                                  int* __restrict__ cnt) {
    unsigned i = blockIdx.x * blockDim.x + threadIdx.x;
    if (i < HSIZE) tab[i] = EMPTY64;
    if (i == 0) *cnt = 0;
}

__global__ __launch_bounds__(256) void hash_insert(const int* __restrict__ coors, int n,
                                                   unsigned long long* __restrict__ tab) {
    int i = blockIdx.x * blockDim.x + threadIdx.x;
    if (i >= n) return;
    int b = coors[4 * i], z = coors[4 * i + 1], y = coors[4 * i + 2], x = coors[4 * i + 3];
    unsigned lin = (((unsigned)b * CD + (unsigned)z) * CH + (unsigned)y) * CW + (unsigned)x;
    unsigned h = (lin * 2654435761u) >> (32u - HBITS);
    unsigned long long rec = ((unsigned long long)(unsigned)i << 32) | (unsigned long long)lin;
    while (true) {
        unsigned long long prev = atomicCAS(&tab[h], EMPTY64, rec);
        if (prev == EMPTY64) break;
        h = (h + 1u) & HMASK;
    }
}

__device__ __forceinline__ int hash_lookup(unsigned lin, const unsigned long long* __restrict__ tab) {
    unsigned h = (lin * 2654435761u) >> (32u - HBITS);
    while (true) {
        unsigned long long v = tab[h];
        if ((unsigned)v == lin) return (int)(v >> 32);
        if (v == EMPTY64) return -1;
        h = (h + 1u) & HMASK;
    }
}

// ---------------- compact extras: (i,k,j) for valid non-center taps ----------------
// mirror symmetry: (i,k,j) valid  <=>  (j,26-k,i) valid  -> scan only k<13, emit both.

__global__ __launch_bounds__(256) void build_extras(const int* __restrict__ coors, int n,
                                                    const unsigned long long* __restrict__ tab,
                                                    int2* __restrict__ extras,
                                                    int* __restrict__ cnt) {
    int i = blockIdx.x * blockDim.x + threadIdx.x;
    if (i >= n) return;
    int b = coors[4 * i], z = coors[4 * i + 1], y = coors[4 * i + 2], x = coors[4 * i + 3];
    for (int k = 0; k < 13; ++k) {
        int dz = k / 9 - 1, dy = (k / 3) % 3 - 1, dx = k % 3 - 1;
        int nz = z + dz, ny = y + dy, nx = x + dx;
        if (nz < 0 || nz >= CD || ny < 0 || ny >= CH || nx < 0 || nx >= CW) continue;
        unsigned lin = (((unsigned)b * CD + (unsigned)nz) * CH + (unsigned)ny) * CW + (unsigned)nx;
        int j = hash_lookup(lin, tab);
        if (j >= 0) {
            int pos = atomicAdd(cnt, 2);          // pos always even; ECAP even -> no straddle
            if (pos + 1 < ECAP) {
                extras[pos]     = make_int2((i << 5) | k,        j);
                extras[pos + 1] = make_int2((j << 5) | (26 - k), i);
            }
        }
    }
}

// ---------------- dense center-tap GEMM: out = x @ W13 ----------------
// Two waves per 64-point chunk; lane = point; each wave computes a uniform half of
// the 64 out-channels (h via readfirstlane => W address is wave-uniform => scalar loads,
// FMA reads W from SGPR: 64 FLOP per v_fmac wave-instruction).

__global__ __launch_bounds__(256) void dense_center(const float* __restrict__ xin,
                                                    float* __restrict__ xout,
                                                    const float* __restrict__ W13, // [64][64]
                                                    int n) {
    int wave = (int)(blockIdx.x * 4u + (threadIdx.x >> 6));
    int lane = threadIdx.x & 63;
    int chunk = wave >> 1;
    int h = __builtin_amdgcn_readfirstlane(wave & 1) * 32;   // provably uniform half-select
    int p = chunk * 64 + lane;
    bool act = p < n;
    int pc = act ? p : (n - 1);

    // x row -> 64 VGPRs (fully static indexing after unroll)
    float xr[64];
    const float4* X4 = (const float4*)(xin + (size_t)pc * 64);
#pragma unroll
    for (int t = 0; t < 16; ++t) ((float4*)xr)[t] = X4[t];

    float* outp = xout + (size_t)pc * 64 + h;
#pragma unroll 1
    for (int g = 0; g < 2; ++g) {
        float acc[16];
#pragma unroll
        for (int o = 0; o < 16; ++o) acc[o] = 0.f;
#pragma unroll
        for (int c = 0; c < 64; ++c) {
            float xc = xr[c];
            const float* wr = W13 + c * 64 + h + g * 16;     // uniform -> s_load
#pragma unroll
            for (int o = 0; o < 16; ++o) acc[o] = fmaf(xc, wr[o], acc[o]);
        }
        if (act) {
#pragma unroll
            for (int t = 0; t < 4; ++t)
                ((float4*)(outp + g * 16))[t] = *(const float4*)&acc[4 * t];
        }
    }
}

// ---------------- sparse residual: out[i] += x[j] @ W[k] for each extra pair ----------------

__global__ __launch_bounds__(256) void residual(const float* __restrict__ xin,
                                                float* __restrict__ xout,
                                                const float* __restrict__ Wl,   // [27][64][64]
                                                const int2* __restrict__ extras,
                                                const int* __restrict__ cnt) {
    int m = *cnt; if (m > ECAP) m = ECAP;
    int nw = (int)((gridDim.x * blockDim.x) >> 6);
    int gw = (int)((blockIdx.x * blockDim.x + threadIdx.x) >> 6);
    int lane = threadIdx.x & 63;
    for (int e = gw; e < m; e += nw) {
        int2 pr = extras[e];
        int i = pr.x >> 5, k = pr.x & 31, j = pr.y;
        float xj = xin[(size_t)j * 64 + lane];
        const float* Wk = Wl + k * 4096;
        float acc = 0.f;
#pragma unroll
        for (int c = 0; c < 64; ++c)
            acc = fmaf(__shfl(xj, c), Wk[c * 64 + lane], acc);
        atomicAdd(&xout[(size_t)i * 64 + lane], acc);
    }
}

// ---------------- launch ----------------

extern "C" void kernel_launch(void* const* d_in, const int* in_sizes, int n_in,
                              void* d_out, int out_size, void* d_ws, size_t ws_size,
                              hipStream_t stream) {
    const float* features = (const float*)d_in[0];
    const float* Ws       = (const float*)d_in[1];   // [3][27][64][64]
    const int*   coors    = (const int*)d_in[2];
    int n = in_sizes[0] / 64;

    // workspace layout: tab (4MB) | cnt (16B) | extras (8MB) | bufA (n*64 f32)
    unsigned long long* tab = (unsigned long long*)d_ws;
    int*   cnt    = (int*)(tab + HSIZE);
    int2*  extras = (int2*)((char*)d_ws + (size_t)HSIZE * 8 + 16);
    float* bufA   = (float*)(extras + ECAP);
    float* out    = (float*)d_out;

    fill_table<<<(HSIZE + 255) / 256, 256, 0, stream>>>(tab, cnt);
    hash_insert<<<(n + 255) / 256, 256, 0, stream>>>(coors, n, tab);
    build_extras<<<(n + 255) / 256, 256, 0, stream>>>(coors, n, tab, extras, cnt);

    int chunks = (n + 63) / 64;
    int waves  = 2 * chunks;
    int dblocks = (waves + 3) / 4;
    const int RBLK = 128;   // residual grid-stride blocks

    const float* W0 = Ws + 0 * 27 * 4096;
    const float* W1 = Ws + 1 * 27 * 4096;
    const float* W2 = Ws + 2 * 27 * 4096;

    // layer 0: features -> out
    dense_center<<<dblocks, 256, 0, stream>>>(features, out, W0 + 13 * 4096, n);
    residual<<<RBLK, 256, 0, stream>>>(features, out, W0, extras, cnt);
    // layer 1: out -> bufA
    dense_center<<<dblocks, 256, 0, stream>>>(out, bufA, W1 + 13 * 4096, n);
    residual<<<RBLK, 256, 0, stream>>>(out, bufA, W1, extras, cnt);
    // layer 2: bufA -> out
    dense_center<<<dblocks, 256, 0, stream>>>(bufA, out, W2 + 13 * 4096, n);
    residual<<<RBLK, 256, 0, stream>>>(bufA, out, W2, extras, cnt);
}